// Round 2
// baseline (210.609 us; speedup 1.0000x reference)
//
#include <hip/hip_runtime.h>
#include <math.h>

#define NB 32              // batch
#define HW (1024 * 1024)   // pixels per image
#define BINS 64            // MAX_INST
#define KLBL 64            // labels per image
#define NCLS 8             // lesion classes
#define BPI 64             // blocks per image for histogram
#define TPB 256

// ---------------------------------------------------------------------------
// Histogram: hist[b][i] = #pixels in mask[b] equal to i  (i < 64)
// Per-wave LDS sub-histograms to reduce shared-atomic contention; int4 loads
// for 16B/lane coalescing. One global atomicAdd per (block, bin) at the end.
// ---------------------------------------------------------------------------
__global__ __launch_bounds__(TPB) void hist_kernel(const int* __restrict__ mask,
                                                   int* __restrict__ hist) {
    __shared__ int sh[4][BINS];
    const int tid = threadIdx.x;
    const int b = blockIdx.x / BPI;
    const int part = blockIdx.x % BPI;
    const int wave = tid >> 6;

    sh[tid >> 6][tid & 63] = 0;   // 256 threads cover 4*64 entries
    __syncthreads();

    const int4* __restrict__ p = (const int4*)(mask + (size_t)b * HW);
    const int n4 = HW / 4;        // 262144 int4 per image
    for (int i = part * TPB + tid; i < n4; i += BPI * TPB) {
        int4 v = p[i];
        atomicAdd(&sh[wave][v.x & 63], 1);
        atomicAdd(&sh[wave][v.y & 63], 1);
        atomicAdd(&sh[wave][v.z & 63], 1);
        atomicAdd(&sh[wave][v.w & 63], 1);
    }
    __syncthreads();

    if (tid < BINS) {
        int s = sh[0][tid] + sh[1][tid] + sh[2][tid] + sh[3][tid];
        atomicAdd(&hist[b * BINS + tid], s);
    }
}

// ---------------------------------------------------------------------------
// Finalize: gather sizes via label_gt, scatter into per-class counts, clamp,
// BCE-with-logits, mean over B*NCLS = 256 elements. Single block, 256 threads.
// NOTE: harness delivers integer inputs as int32 — label_gt is 4096 int32s,
// entry e: inst = lg[2e], label = lg[2e+1].
// ---------------------------------------------------------------------------
__global__ __launch_bounds__(TPB) void finalize_kernel(const float* __restrict__ pred,
                                                       const int* __restrict__ lg,
                                                       const int* __restrict__ hist,
                                                       float* __restrict__ out) {
    __shared__ float cnts[NB * NCLS];   // 256
    __shared__ float wsum[4];
    const int tid = threadIdx.x;

    cnts[tid] = 0.0f;
    __syncthreads();

    // B*K = 2048 (b,k) entries; 8 per thread.
    for (int e = tid; e < NB * KLBL; e += TPB) {
        int inst  = lg[e * 2 + 0];
        int label = lg[e * 2 + 1];
        if (label > 0 && label <= NCLS) {
            float sz = (float)hist[(e >> 6) * BINS + (inst & 63)];
            atomicAdd(&cnts[(e >> 6) * NCLS + (label - 1)], sz);
        }
    }
    __syncthreads();

    float x = pred[tid];
    float t = fminf(cnts[tid] * (1.0f / 100.0f), 1.0f);
    float l = fmaxf(x, 0.0f) - x * t + log1pf(expf(-fabsf(x)));

    // wave(64) shuffle reduction, then combine 4 waves via LDS
    for (int off = 32; off > 0; off >>= 1)
        l += __shfl_down(l, off, 64);
    if ((tid & 63) == 0) wsum[tid >> 6] = l;
    __syncthreads();
    if (tid == 0)
        out[0] = (wsum[0] + wsum[1] + wsum[2] + wsum[3]) * (1.0f / (NB * NCLS));
}

extern "C" void kernel_launch(void* const* d_in, const int* in_sizes, int n_in,
                              void* d_out, int out_size, void* d_ws, size_t ws_size,
                              hipStream_t stream) {
    const float* pred = (const float*)d_in[0];    // [32, 8] fp32
    const int*   mask = (const int*)d_in[1];      // [32, 1024, 1024] int32
    const int*   lg   = (const int*)d_in[2];      // [32, 64, 2] delivered as int32
    float* out = (float*)d_out;
    int* hist = (int*)d_ws;                       // [32][64] int32 = 8 KB

    hipMemsetAsync(hist, 0, NB * BINS * sizeof(int), stream);
    hist_kernel<<<NB * BPI, TPB, 0, stream>>>(mask, hist);
    finalize_kernel<<<1, TPB, 0, stream>>>(pred, lg, hist, out);
}